// Round 1
// baseline (22546.637 us; speedup 1.0000x reference)
//
#include <hip/hip_runtime.h>
#include <hip/hip_bf16.h>

#define B_  128
#define T_  512
#define HID 512     // H = I = 512
#define NG  1536    // 3H
#define GK  32      // k-slice groups (16 neurons/gate per WG)
#define GB  8       // batch groups  (16 batches per WG)

typedef __attribute__((ext_vector_type(8))) short bf16x8;
typedef __attribute__((ext_vector_type(4))) float f32x4;

__device__ __forceinline__ float bf2f(unsigned short h) {
  union { unsigned u; float f; } c; c.u = ((unsigned)h) << 16; return c.f;
}
__device__ __forceinline__ unsigned short f2bf_rn(float f) {
  union { float f; unsigned u; } c; c.f = f;
  return (unsigned short)((c.u + 0x7FFFu + ((c.u >> 16) & 1u)) >> 16);
}
// split fp32 -> hi (truncated bf16) + lo (rn bf16 of residual); hi+lo ~ fp32
__device__ __forceinline__ void split1(float f, short& hi, short& lo) {
  union { float f; unsigned u; } c; c.f = f;
  unsigned short h = (unsigned short)(c.u >> 16);
  float r = f - bf2f(h);
  hi = (short)h; lo = (short)f2bf_rn(r);
}
__device__ __forceinline__ void split8(float4 a, float4 b, bf16x8& hi, bf16x8& lo) {
  float v[8] = {a.x,a.y,a.z,a.w,b.x,b.y,b.z,b.w};
  #pragma unroll
  for (int i = 0; i < 8; ++i) { short h,l; split1(v[i],h,l); hi[i]=h; lo[i]=l; }
}

// ---------------------------------------------------------------------------
// Kernel 0: split h0 (fp32) into (hi,lo) bf16 planes at parity 1
// hbuf layout: [(parity*2 + hl) * 65536 + b*512 + j] ushort
// ---------------------------------------------------------------------------
__global__ void h0_split(const float* __restrict__ h0, unsigned short* __restrict__ hbuf) {
  int i = blockIdx.x * 256 + threadIdx.x;        // 65536 threads
  float f = h0[i];
  short hi, lo; split1(f, hi, lo);
  hbuf[(1*2+0)*65536 + i] = (unsigned short)hi;
  hbuf[(1*2+1)*65536 + i] = (unsigned short)lo;
}

// ---------------------------------------------------------------------------
// Kernel 1: x_lin[m][n] = sum_k x[m][k]*Wx[n][k] + bx[n]
// M=65536, N=1536, K=512.  WG = 128x128 tile (2x2 waves of 64x64).
// 3-term split-bf16 MFMA (near-fp32 accuracy).
// ---------------------------------------------------------------------------
template<bool WSF32>
__global__ __launch_bounds__(256) void xlin_kernel(const float* __restrict__ x,
                                                   const float* __restrict__ Wx,
                                                   const float* __restrict__ bx,
                                                   void* __restrict__ xlin) {
  const int lane = threadIdx.x & 63;
  const int w    = threadIdx.x >> 6;
  const int wm   = w & 1, wn = w >> 1;
  const int quad = lane >> 4, l16 = lane & 15;
  const long m0  = (long)blockIdx.y * 128;
  const int  n0  = blockIdx.x * 128;

  f32x4 acc[4][4];
  #pragma unroll
  for (int i = 0; i < 4; ++i)
    #pragma unroll
    for (int j = 0; j < 4; ++j) acc[i][j] = (f32x4){0.f,0.f,0.f,0.f};

  for (int kk = 0; kk < 16; ++kk) {
    const int kq = kk*32 + quad*8;
    bf16x8 ahi[4], alo[4], bhi[4], blo[4];
    #pragma unroll
    for (int i = 0; i < 4; ++i) {
      const float* p = x + (m0 + wm*64 + i*16 + l16) * HID + kq;
      float4 f0 = ((const float4*)p)[0], f1 = ((const float4*)p)[1];
      split8(f0, f1, ahi[i], alo[i]);
      const float* q = Wx + (long)(n0 + wn*64 + i*16 + l16) * HID + kq;
      float4 g0 = ((const float4*)q)[0], g1 = ((const float4*)q)[1];
      split8(g0, g1, bhi[i], blo[i]);
    }
    #pragma unroll
    for (int i = 0; i < 4; ++i)
      #pragma unroll
      for (int j = 0; j < 4; ++j) {
        acc[i][j] = __builtin_amdgcn_mfma_f32_16x16x32_bf16(ahi[i], bhi[j], acc[i][j], 0, 0, 0);
        acc[i][j] = __builtin_amdgcn_mfma_f32_16x16x32_bf16(ahi[i], blo[j], acc[i][j], 0, 0, 0);
        acc[i][j] = __builtin_amdgcn_mfma_f32_16x16x32_bf16(alo[i], bhi[j], acc[i][j], 0, 0, 0);
      }
  }
  // epilogue: C row = quad*4+reg (m), col = l16 (n)
  #pragma unroll
  for (int i = 0; i < 4; ++i) {
    #pragma unroll
    for (int j = 0; j < 4; ++j) {
      const int n = n0 + wn*64 + j*16 + l16;
      const float bias = bx[n];
      #pragma unroll
      for (int r = 0; r < 4; ++r) {
        const long m = m0 + wm*64 + i*16 + quad*4 + r;
        const float v = acc[i][j][r] + bias;
        if (WSF32) ((float*)xlin)[m * NG + n] = v;
        else       ((unsigned short*)xlin)[m * NG + n] = f2bf_rn(v);
      }
    }
  }
}

// ---------------------------------------------------------------------------
// Kernel 2: persistent GRU recurrence.
// 256 WGs = 32 k-slices x 8 batch-groups; WG = 256 thr = 4 waves.
// Wh fragments live in VGPRs (split-bf16, 3-term). h double-buffered in global
// as pre-split (hi,lo) bf16. Sync: per-(t, batch-group) release/acquire ctr.
// ---------------------------------------------------------------------------
template<bool WSF32>
__global__ __launch_bounds__(256) void gru_rec(const void* __restrict__ xlin,
                                               const float* __restrict__ Wh,
                                               unsigned short* __restrict__ hbuf,
                                               unsigned* __restrict__ cnt,
                                               float* __restrict__ out) {
  __shared__ float red[3][4][16][16];   // [gate][wave][b][k]
  const int tid  = threadIdx.x;
  const int lane = tid & 63;
  const int w    = tid >> 6;
  const int quad = lane >> 4, l16 = lane & 15;
  const int kc   = blockIdx.x & 31;     // k-slice
  const int cb   = blockIdx.x >> 5;     // batch group

  // Preload Wh fragments for this WG's (k-slice, wave K-range) into registers.
  // B-operand element (k=quad*8+j, n=l16) = Wh[gate*512 + kc*16 + l16][j_abs]
  bf16x8 Bhi[3][4], Blo[3][4];
  #pragma unroll
  for (int g = 0; g < 3; ++g)
    #pragma unroll
    for (int kk = 0; kk < 4; ++kk) {
      const float* p = Wh + (long)(g*HID + kc*16 + l16) * HID + w*128 + kk*32 + quad*8;
      float4 f0 = ((const float4*)p)[0], f1 = ((const float4*)p)[1];
      split8(f0, f1, Bhi[g][kk], Blo[g][kk]);
    }

  const int bb   = tid >> 4;            // 0..15 local batch (gates phase)
  const int kk_  = tid & 15;            // 0..15 local neuron (gates phase)
  const int brow = cb*16 + bb;          // global batch
  const int ncol = kc*16 + kk_;         // global neuron
  float* yout = out;
  float* hfin = out + (long)B_ * T_ * HID;

  for (int t = 0; t < T_; ++t) {
    if (t > 0) {
      if (tid == 0) {
        while (__hip_atomic_load(&cnt[(t-1)*GB + cb], __ATOMIC_ACQUIRE,
                                 __HIP_MEMORY_SCOPE_AGENT) < (unsigned)GK)
          __builtin_amdgcn_s_sleep(1);
      }
      __syncthreads();
    }

    // x_lin prefetch for this thread's (b, k)
    float xz, xr, xn;
    {
      const long mrow = (long)brow * T_ + t;
      if (WSF32) {
        const float* xp = (const float*)xlin + mrow * NG + ncol;
        xz = xp[0]; xr = xp[HID]; xn = xp[2*HID];
      } else {
        const unsigned short* xp = (const unsigned short*)xlin + mrow * NG + ncol;
        xz = bf2f(xp[0]); xr = bf2f(xp[HID]); xn = bf2f(xp[2*HID]);
      }
    }

    const int par_r = (t+1) & 1, par_w = t & 1;
    const unsigned short* rHi = hbuf + (par_r*2+0)*65536;
    const unsigned short* rLo = hbuf + (par_r*2+1)*65536;

    // GEMM: this wave covers K-slice [w*128, w*128+128)
    f32x4 acc[3] = { (f32x4){0,0,0,0}, (f32x4){0,0,0,0}, (f32x4){0,0,0,0} };
    #pragma unroll
    for (int kk = 0; kk < 4; ++kk) {
      const int off = (cb*16 + l16)*HID + w*128 + kk*32 + quad*8;
      bf16x8 ah = *(const bf16x8*)(rHi + off);
      bf16x8 al = *(const bf16x8*)(rLo + off);
      #pragma unroll
      for (int g = 0; g < 3; ++g) {
        acc[g] = __builtin_amdgcn_mfma_f32_16x16x32_bf16(ah, Bhi[g][kk], acc[g], 0, 0, 0);
        acc[g] = __builtin_amdgcn_mfma_f32_16x16x32_bf16(ah, Blo[g][kk], acc[g], 0, 0, 0);
        acc[g] = __builtin_amdgcn_mfma_f32_16x16x32_bf16(al, Bhi[g][kk], acc[g], 0, 0, 0);
      }
    }
    #pragma unroll
    for (int g = 0; g < 3; ++g)
      #pragma unroll
      for (int r = 0; r < 4; ++r)
        red[g][w][quad*4 + r][l16] = acc[g][r];

    // exact-ish h_prev for this thread's element (hi+lo reconstruction)
    float hp;
    { const int off = brow*HID + ncol; hp = bf2f(rHi[off]) + bf2f(rLo[off]); }

    __syncthreads();

    float az = 0.f, ar = 0.f, an = 0.f;
    #pragma unroll
    for (int ww = 0; ww < 4; ++ww) {
      az += red[0][ww][bb][kk_];
      ar += red[1][ww][bb][kk_];
      an += red[2][ww][bb][kk_];
    }
    const float z = 1.f / (1.f + __expf(-(az + xz)));
    const float r = 1.f / (1.f + __expf(-(ar + xr)));
    const float pre = xn + r * an;
    const float e2 = __expf(-2.f * pre);
    const float n = 2.f / (1.f + e2) - 1.f;          // tanh, inf-safe both tails
    const float hn = (1.f - z) * n + z * hp;

    yout[((long)brow * T_ + t) * HID + ncol] = hn;
    if (t < T_ - 1) {
      unsigned short* wHi = hbuf + (par_w*2+0)*65536;
      unsigned short* wLo = hbuf + (par_w*2+1)*65536;
      const int off = brow*HID + ncol;
      short hi, lo; split1(hn, hi, lo);
      wHi[off] = (unsigned short)hi;
      wLo[off] = (unsigned short)lo;
    } else {
      hfin[brow*HID + ncol] = hn;
    }

    __threadfence();     // release our h writes to device scope
    __syncthreads();
    if (tid == 0 && t < T_ - 1)
      __hip_atomic_fetch_add(&cnt[t*GB + cb], 1u, __ATOMIC_RELEASE,
                             __HIP_MEMORY_SCOPE_AGENT);
  }
}

// ---------------------------------------------------------------------------
extern "C" void kernel_launch(void* const* d_in, const int* in_sizes, int n_in,
                              void* d_out, int out_size, void* d_ws, size_t ws_size,
                              hipStream_t stream) {
  const float* x  = (const float*)d_in[0];
  const float* h0 = (const float*)d_in[1];
  const float* Wx = (const float*)d_in[2];
  const float* bx = (const float*)d_in[3];
  const float* Wh = (const float*)d_in[4];
  float* out = (float*)d_out;

  const size_t xlin_f32  = (size_t)B_ * T_ * NG * 4;   // 402,653,184
  const size_t xlin_bf16 = (size_t)B_ * T_ * NG * 2;   // 201,326,592
  const size_t hbuf_sz   = (size_t)4 * 65536 * 2;      // 512 KiB
  const size_t cnt_sz    = (size_t)T_ * GB * 4;        // 16 KiB

  const bool wsf32 = (ws_size >= xlin_f32 + hbuf_sz + cnt_sz);
  const size_t xsz = wsf32 ? xlin_f32 : xlin_bf16;
  void* xlin = d_ws;
  unsigned short* hbuf = (unsigned short*)((char*)d_ws + xsz);
  unsigned* cnt = (unsigned*)((char*)d_ws + xsz + hbuf_sz);

  hipMemsetAsync(cnt, 0, cnt_sz, stream);
  h0_split<<<256, 256, 0, stream>>>(h0, hbuf);
  if (wsf32) {
    xlin_kernel<true ><<<dim3(12, 512), 256, 0, stream>>>(x, Wx, bx, xlin);
    gru_rec<true >    <<<256, 256, 0, stream>>>(xlin, Wh, hbuf, cnt, out);
  } else {
    xlin_kernel<false><<<dim3(12, 512), 256, 0, stream>>>(x, Wx, bx, xlin);
    gru_rec<false>    <<<256, 256, 0, stream>>>(xlin, Wh, hbuf, cnt, out);
  }
}

// Round 3
// 7856.242 us; speedup vs baseline: 2.8699x; 2.8699x over previous
//
#include <hip/hip_runtime.h>
#include <hip/hip_bf16.h>

#define B_  128
#define T_  512
#define HID 512     // H = I = 512
#define NG  1536    // 3H
#define GK  32      // WGs per batch group (16 neurons x 3 gates each)
#define GB  8       // batch groups (16 batches each)
#define CSTRIDE 16  // counter padding: 16 uints = 64B

typedef __attribute__((ext_vector_type(8))) short bf16x8;
typedef __attribute__((ext_vector_type(4))) float f32x4;
typedef unsigned int uint;

__device__ __forceinline__ float bf2f(unsigned short h) {
  union { unsigned u; float f; } c; c.u = ((unsigned)h) << 16; return c.f;
}
__device__ __forceinline__ unsigned short f2bf_rn(float f) {
  union { float f; unsigned u; } c; c.f = f;
  return (unsigned short)((c.u + 0x7FFFu + ((c.u >> 16) & 1u)) >> 16);
}
// split fp32 -> hi (truncated bf16) + lo (rn bf16 of residual); hi+lo ~ fp32
__device__ __forceinline__ void split1(float f, short& hi, short& lo) {
  union { float f; unsigned u; } c; c.f = f;
  unsigned short h = (unsigned short)(c.u >> 16);
  float r = f - bf2f(h);
  hi = (short)h; lo = (short)f2bf_rn(r);
}
__device__ __forceinline__ void split8(float4 a, float4 b, bf16x8& hi, bf16x8& lo) {
  float v[8] = {a.x,a.y,a.z,a.w,b.x,b.y,b.z,b.w};
  #pragma unroll
  for (int i = 0; i < 8; ++i) { short h,l; split1(v[i],h,l); hi[i]=h; lo[i]=l; }
}
// pack fp32 as (hi_bf16 << 16) | lo_bf16
__device__ __forceinline__ uint packh(float f) {
  short hi, lo; split1(f, hi, lo);
  return (((uint)(unsigned short)hi) << 16) | (uint)(unsigned short)lo;
}
__device__ __forceinline__ float unpackh(uint u) {
  return bf2f((unsigned short)(u >> 16)) + bf2f((unsigned short)(u & 0xFFFFu));
}

// ---------------------------------------------------------------------------
// Kernel 0: pack h0 (fp32) into parity-1 packed buffer
// hbuf layout: [parity * 65536 + b*512 + j] uint (hi<<16 | lo)
// ---------------------------------------------------------------------------
__global__ void h0_pack(const float* __restrict__ h0, uint* __restrict__ hbuf) {
  int i = blockIdx.x * 256 + threadIdx.x;        // 65536 threads
  hbuf[65536 + i] = packh(h0[i]);
}

// ---------------------------------------------------------------------------
// Kernel 1: x_lin[m][n] = sum_k x[m][k]*Wx[n][k] + bx[n]
// M=65536, N=1536, K=512.  WG = 128x128 tile (2x2 waves of 64x64).
// 3-term split-bf16 MFMA (near-fp32 accuracy).
// ---------------------------------------------------------------------------
template<bool WSF32>
__global__ __launch_bounds__(256) void xlin_kernel(const float* __restrict__ x,
                                                   const float* __restrict__ Wx,
                                                   const float* __restrict__ bx,
                                                   void* __restrict__ xlin) {
  const int lane = threadIdx.x & 63;
  const int w    = threadIdx.x >> 6;
  const int wm   = w & 1, wn = w >> 1;
  const int quad = lane >> 4, l16 = lane & 15;
  const long m0  = (long)blockIdx.y * 128;
  const int  n0  = blockIdx.x * 128;

  f32x4 acc[4][4];
  #pragma unroll
  for (int i = 0; i < 4; ++i)
    #pragma unroll
    for (int j = 0; j < 4; ++j) acc[i][j] = (f32x4){0.f,0.f,0.f,0.f};

  for (int kk = 0; kk < 16; ++kk) {
    const int kq = kk*32 + quad*8;
    bf16x8 ahi[4], alo[4], bhi[4], blo[4];
    #pragma unroll
    for (int i = 0; i < 4; ++i) {
      const float* p = x + (m0 + wm*64 + i*16 + l16) * HID + kq;
      float4 f0 = ((const float4*)p)[0], f1 = ((const float4*)p)[1];
      split8(f0, f1, ahi[i], alo[i]);
      const float* q = Wx + (long)(n0 + wn*64 + i*16 + l16) * HID + kq;
      float4 g0 = ((const float4*)q)[0], g1 = ((const float4*)q)[1];
      split8(g0, g1, bhi[i], blo[i]);
    }
    #pragma unroll
    for (int i = 0; i < 4; ++i)
      #pragma unroll
      for (int j = 0; j < 4; ++j) {
        acc[i][j] = __builtin_amdgcn_mfma_f32_16x16x32_bf16(ahi[i], bhi[j], acc[i][j], 0, 0, 0);
        acc[i][j] = __builtin_amdgcn_mfma_f32_16x16x32_bf16(ahi[i], blo[j], acc[i][j], 0, 0, 0);
        acc[i][j] = __builtin_amdgcn_mfma_f32_16x16x32_bf16(alo[i], bhi[j], acc[i][j], 0, 0, 0);
      }
  }
  // epilogue: C row = quad*4+reg (m), col = l16 (n)
  #pragma unroll
  for (int i = 0; i < 4; ++i) {
    #pragma unroll
    for (int j = 0; j < 4; ++j) {
      const int n = n0 + wn*64 + j*16 + l16;
      const float bias = bx[n];
      #pragma unroll
      for (int r = 0; r < 4; ++r) {
        const long m = m0 + wm*64 + i*16 + quad*4 + r;
        const float v = acc[i][j][r] + bias;
        if (WSF32) ((float*)xlin)[m * NG + n] = v;
        else       ((unsigned short*)xlin)[m * NG + n] = f2bf_rn(v);
      }
    }
  }
}

// ---------------------------------------------------------------------------
// Kernel 2: persistent GRU recurrence.
// 256 WGs = 32 neuron-slices x 8 batch-groups; WG = 256 thr = 4 waves.
// Wh resident in VGPRs (split-bf16, 3-term). h double-buffered in global as
// packed (hi<<16|lo) uint.
//
// Sync protocol (proper release/acquire, minimum frequency):
//   writer: plain h stores -> __syncthreads (drains vmcnt)
//           -> tid0: fetch_add(RELEASE, agent)   [emits wbl2: L2 -> LLC]
//   reader: tid0 polls RELAXED (proven live in R2; no inv storm)
//           -> tid0: one ACQUIRE load            [emits inv: kill stale L0/L2]
//           -> __syncthreads -> plain VECTORIZED h loads (fresh fetch)
// ---------------------------------------------------------------------------
template<bool WSF32>
__global__ __launch_bounds__(256, 1) void gru_rec(const void* __restrict__ xlin,
                                                  const float* __restrict__ Wh,
                                                  uint* __restrict__ hbuf,
                                                  uint* __restrict__ cnt,
                                                  float* __restrict__ out) {
  __shared__ float red[3][4][16][16];   // [gate][wave][b][k]
  const int tid  = threadIdx.x;
  const int lane = tid & 63;
  const int w    = tid >> 6;
  const int quad = lane >> 4, l16 = lane & 15;
  const int kc   = blockIdx.x & 31;     // neuron slice
  const int cb   = blockIdx.x >> 5;     // batch group

  // Preload Wh fragments for this WG's (neuron-slice, wave K-range) into regs.
  // B-operand element (k=quad*8+j, n=l16) = Wh[gate*512 + kc*16 + l16][k_abs]
  bf16x8 Bhi[3][4], Blo[3][4];
  #pragma unroll
  for (int g = 0; g < 3; ++g)
    #pragma unroll
    for (int kk = 0; kk < 4; ++kk) {
      const float* p = Wh + (long)(g*HID + kc*16 + l16) * HID + w*128 + kk*32 + quad*8;
      float4 f0 = ((const float4*)p)[0], f1 = ((const float4*)p)[1];
      split8(f0, f1, Bhi[g][kk], Blo[g][kk]);
    }

  const int bb   = tid >> 4;            // 0..15 local batch (gates phase)
  const int kk_  = tid & 15;            // 0..15 local neuron (gates phase)
  const int brow = cb*16 + bb;          // global batch
  const int ncol = kc*16 + kk_;         // global neuron
  float* yout = out;
  float* hfin = out + (long)B_ * T_ * HID;

  uint* const hb0 = hbuf;
  uint* const hb1 = hbuf + 65536;

  for (int t = 0; t < T_; ++t) {
    // --- x_lin prefetch: independent of h, issue BEFORE the spin ---
    float xz, xr, xn;
    {
      const long mrow = (long)brow * T_ + t;
      if (WSF32) {
        const float* xp = (const float*)xlin + mrow * NG + ncol;
        xz = xp[0]; xr = xp[HID]; xn = xp[2*HID];
      } else {
        const unsigned short* xp = (const unsigned short*)xlin + mrow * NG + ncol;
        xz = bf2f(xp[0]); xr = bf2f(xp[HID]); xn = bf2f(xp[2*HID]);
      }
    }

    if (t > 0) {
      if (tid == 0) {
        uint* cp = &cnt[((t-1)*GB + cb) * CSTRIDE];
        while (__hip_atomic_load(cp, __ATOMIC_RELAXED,
                                 __HIP_MEMORY_SCOPE_AGENT) < (unsigned)GK)
          __builtin_amdgcn_s_sleep(2);
        // single acquire: buffer_inv -> subsequent plain loads fetch fresh
        (void)__hip_atomic_load(cp, __ATOMIC_ACQUIRE, __HIP_MEMORY_SCOPE_AGENT);
      }
      __syncthreads();
    }

    const uint* rb = ((t + 1) & 1) ? hb1 : hb0;
    uint*       wb = (t & 1)       ? hb1 : hb0;

    // --- plain VECTORIZED h loads (fresh after the acquire-inv) ---
    const uint4* hv = (const uint4*)(rb + (cb*16 + l16)*HID + w*128 + quad*8);
    uint4 u[4][2];
    #pragma unroll
    for (int kk = 0; kk < 4; ++kk) {
      u[kk][0] = hv[kk*8 + 0];          // +kk*32 uints
      u[kk][1] = hv[kk*8 + 1];
    }
    const uint hpu = rb[brow*HID + ncol];

    // --- GEMM: this wave covers K-slice [w*128, w*128+128) ---
    f32x4 acc[3] = { (f32x4){0,0,0,0}, (f32x4){0,0,0,0}, (f32x4){0,0,0,0} };
    #pragma unroll
    for (int kk = 0; kk < 4; ++kk) {
      bf16x8 ah, al;
      #pragma unroll
      for (int i = 0; i < 4; ++i) {
        uint v0 = ((const uint*)&u[kk][0])[i];
        uint v1 = ((const uint*)&u[kk][1])[i];
        ah[i]   = (short)(v0 >> 16); al[i]   = (short)(v0 & 0xFFFFu);
        ah[i+4] = (short)(v1 >> 16); al[i+4] = (short)(v1 & 0xFFFFu);
      }
      #pragma unroll
      for (int g = 0; g < 3; ++g) {
        acc[g] = __builtin_amdgcn_mfma_f32_16x16x32_bf16(ah, Bhi[g][kk], acc[g], 0, 0, 0);
        acc[g] = __builtin_amdgcn_mfma_f32_16x16x32_bf16(ah, Blo[g][kk], acc[g], 0, 0, 0);
        acc[g] = __builtin_amdgcn_mfma_f32_16x16x32_bf16(al, Bhi[g][kk], acc[g], 0, 0, 0);
      }
    }
    #pragma unroll
    for (int g = 0; g < 3; ++g)
      #pragma unroll
      for (int r = 0; r < 4; ++r)
        red[g][w][quad*4 + r][l16] = acc[g][r];

    const float hp = unpackh(hpu);

    __syncthreads();

    float az = 0.f, ar = 0.f, an = 0.f;
    #pragma unroll
    for (int ww = 0; ww < 4; ++ww) {
      az += red[0][ww][bb][kk_];
      ar += red[1][ww][bb][kk_];
      an += red[2][ww][bb][kk_];
    }
    const float z = 1.f / (1.f + __expf(-(az + xz)));
    const float r = 1.f / (1.f + __expf(-(ar + xr)));
    const float pre = xn + r * an;
    const float e2 = __expf(-2.f * pre);
    const float n = 2.f / (1.f + e2) - 1.f;          // tanh, inf-safe both tails
    const float hn = (1.f - z) * n + z * hp;

    __builtin_nontemporal_store(hn, &yout[((long)brow * T_ + t) * HID + ncol]);
    if (t < T_ - 1) {
      wb[brow*HID + ncol] = packh(hn);               // plain store
    } else {
      hfin[brow*HID + ncol] = hn;
    }

    // barrier drains vmcnt; then ONE release RMW (emits wbl2 -> h visible at
    // the coherence point before the count becomes observable)
    __syncthreads();
    if (tid == 0 && t < T_ - 1)
      __hip_atomic_fetch_add(&cnt[(t*GB + cb) * CSTRIDE], 1u, __ATOMIC_RELEASE,
                             __HIP_MEMORY_SCOPE_AGENT);
  }
}

// ---------------------------------------------------------------------------
extern "C" void kernel_launch(void* const* d_in, const int* in_sizes, int n_in,
                              void* d_out, int out_size, void* d_ws, size_t ws_size,
                              hipStream_t stream) {
  const float* x  = (const float*)d_in[0];
  const float* h0 = (const float*)d_in[1];
  const float* Wx = (const float*)d_in[2];
  const float* bx = (const float*)d_in[3];
  const float* Wh = (const float*)d_in[4];
  float* out = (float*)d_out;

  const size_t xlin_f32  = (size_t)B_ * T_ * NG * 4;   // 402,653,184
  const size_t xlin_bf16 = (size_t)B_ * T_ * NG * 2;   // 201,326,592
  const size_t hbuf_sz   = (size_t)2 * 65536 * 4;      // 512 KiB (packed uint)
  const size_t cnt_sz    = (size_t)T_ * GB * CSTRIDE * 4; // 256 KiB

  const bool wsf32 = (ws_size >= xlin_f32 + hbuf_sz + cnt_sz);
  const size_t xsz = wsf32 ? xlin_f32 : xlin_bf16;
  void* xlin = d_ws;
  uint* hbuf = (uint*)((char*)d_ws + xsz);
  uint* cnt  = (uint*)((char*)d_ws + xsz + hbuf_sz);

  hipMemsetAsync(cnt, 0, cnt_sz, stream);
  h0_pack<<<256, 256, 0, stream>>>(h0, hbuf);
  if (wsf32) {
    xlin_kernel<true ><<<dim3(12, 512), 256, 0, stream>>>(x, Wx, bx, xlin);
    gru_rec<true >    <<<256, 256, 0, stream>>>(xlin, Wh, hbuf, cnt, out);
  } else {
    xlin_kernel<false><<<dim3(12, 512), 256, 0, stream>>>(x, Wx, bx, xlin);
    gru_rec<false>    <<<256, 256, 0, stream>>>(xlin, Wh, hbuf, cnt, out);
  }
}

// Round 4
// 3498.286 us; speedup vs baseline: 6.4451x; 2.2457x over previous
//
#include <hip/hip_runtime.h>
#include <hip/hip_bf16.h>

#define B_  128
#define T_  512
#define HID 512     // H = I = 512
#define NG  1536    // 3H
#define CSTRIDE 16  // sync-slot padding: 16 uints = 64B

typedef __attribute__((ext_vector_type(8))) short bf16x8;
typedef __attribute__((ext_vector_type(4))) float f32x4;
typedef unsigned int uint;

__device__ __forceinline__ float bf2f(unsigned short h) {
  union { unsigned u; float f; } c; c.u = ((unsigned)h) << 16; return c.f;
}
__device__ __forceinline__ unsigned short f2bf_rn(float f) {
  union { float f; unsigned u; } c; c.f = f;
  return (unsigned short)((c.u + 0x7FFFu + ((c.u >> 16) & 1u)) >> 16);
}
// split fp32 -> hi (truncated bf16) + lo (rn bf16 of residual); hi+lo ~ fp32
__device__ __forceinline__ void split1(float f, short& hi, short& lo) {
  union { float f; unsigned u; } c; c.f = f;
  unsigned short h = (unsigned short)(c.u >> 16);
  float r = f - bf2f(h);
  hi = (short)h; lo = (short)f2bf_rn(r);
}
__device__ __forceinline__ void split8(float4 a, float4 b, bf16x8& hi, bf16x8& lo) {
  float v[8] = {a.x,a.y,a.z,a.w,b.x,b.y,b.z,b.w};
  #pragma unroll
  for (int i = 0; i < 8; ++i) { short h,l; split1(v[i],h,l); hi[i]=h; lo[i]=l; }
}
__device__ __forceinline__ uint packh(float f) {
  short hi, lo; split1(f, hi, lo);
  return (((uint)(unsigned short)hi) << 16) | (uint)(unsigned short)lo;
}
__device__ __forceinline__ float unpackh(uint u) {
  return bf2f((unsigned short)(u >> 16)) + bf2f((unsigned short)(u & 0xFFFFu));
}

__device__ __forceinline__ uint aload_rlx(const uint* p) {
  return __hip_atomic_load(p, __ATOMIC_RELAXED, __HIP_MEMORY_SCOPE_AGENT);
}

// ---------------------------------------------------------------------------
// Kernel 0: pack h0 (fp32) into parity-1 packed buffer
// ---------------------------------------------------------------------------
__global__ void h0_pack(const float* __restrict__ h0, uint* __restrict__ hbuf) {
  int i = blockIdx.x * 256 + threadIdx.x;        // 65536 threads
  hbuf[65536 + i] = packh(h0[i]);
}

// ---------------------------------------------------------------------------
// Kernel 1: x_lin[m][n] = sum_k x[m][k]*Wx[n][k] + bx[n]
// M=65536, N=1536, K=512.  WG = 128x128 tile (2x2 waves of 64x64).
// ---------------------------------------------------------------------------
template<bool WSF32>
__global__ __launch_bounds__(256) void xlin_kernel(const float* __restrict__ x,
                                                   const float* __restrict__ Wx,
                                                   const float* __restrict__ bx,
                                                   void* __restrict__ xlin) {
  const int lane = threadIdx.x & 63;
  const int w    = threadIdx.x >> 6;
  const int wm   = w & 1, wn = w >> 1;
  const int quad = lane >> 4, l16 = lane & 15;
  const long m0  = (long)blockIdx.y * 128;
  const int  n0  = blockIdx.x * 128;

  f32x4 acc[4][4];
  #pragma unroll
  for (int i = 0; i < 4; ++i)
    #pragma unroll
    for (int j = 0; j < 4; ++j) acc[i][j] = (f32x4){0.f,0.f,0.f,0.f};

  for (int kk = 0; kk < 16; ++kk) {
    const int kq = kk*32 + quad*8;
    bf16x8 ahi[4], alo[4], bhi[4], blo[4];
    #pragma unroll
    for (int i = 0; i < 4; ++i) {
      const float* p = x + (m0 + wm*64 + i*16 + l16) * HID + kq;
      float4 f0 = ((const float4*)p)[0], f1 = ((const float4*)p)[1];
      split8(f0, f1, ahi[i], alo[i]);
      const float* q = Wx + (long)(n0 + wn*64 + i*16 + l16) * HID + kq;
      float4 g0 = ((const float4*)q)[0], g1 = ((const float4*)q)[1];
      split8(g0, g1, bhi[i], blo[i]);
    }
    #pragma unroll
    for (int i = 0; i < 4; ++i)
      #pragma unroll
      for (int j = 0; j < 4; ++j) {
        acc[i][j] = __builtin_amdgcn_mfma_f32_16x16x32_bf16(ahi[i], bhi[j], acc[i][j], 0, 0, 0);
        acc[i][j] = __builtin_amdgcn_mfma_f32_16x16x32_bf16(ahi[i], blo[j], acc[i][j], 0, 0, 0);
        acc[i][j] = __builtin_amdgcn_mfma_f32_16x16x32_bf16(alo[i], bhi[j], acc[i][j], 0, 0, 0);
      }
  }
  #pragma unroll
  for (int i = 0; i < 4; ++i) {
    #pragma unroll
    for (int j = 0; j < 4; ++j) {
      const int n = n0 + wn*64 + j*16 + l16;
      const float bias = bx[n];
      #pragma unroll
      for (int r = 0; r < 4; ++r) {
        const long m = m0 + wm*64 + i*16 + quad*4 + r;
        const float v = acc[i][j][r] + bias;
        if (WSF32) ((float*)xlin)[m * NG + n] = v;
        else       ((unsigned short*)xlin)[m * NG + n] = f2bf_rn(v);
      }
    }
  }
}

// ---------------------------------------------------------------------------
// Kernel 2: persistent GRU recurrence with XCD-leader hierarchical sync.
// 256 WGs = 32 neuron-slices x 8 batch-groups. Full-device lockstep per step.
// Per XCD per step: exactly ONE wbl2 (leader release) + ONE inv (leader
// acquire), instead of 32 of each. XCD membership discovered at runtime via
// s_getreg(HW_REG_XCC_ID) -> correctness independent of WG->XCD mapping.
//
// sync layout (uint, CSTRIDE-padded):
//   gcnt(t)   = sync + t*CSTRIDE                 // device step counter
//   lcnt(t,x) = sync + (T_ + t*8+x)*CSTRIDE      // per-XCD step counter
//   flag(t,x) = sync + (T_*9 + t*8+x)*CSTRIDE    // per-XCD "inv done"
//   mem(x)    = sync + (T_*17 + x)*CSTRIDE       // membership count
//   init      = sync + (T_*17 + 8)*CSTRIDE       // one-time barrier
// ---------------------------------------------------------------------------
template<bool WSF32>
__global__ __launch_bounds__(256, 1) void gru_rec(const void* __restrict__ xlin,
                                                  const float* __restrict__ Wh,
                                                  uint* __restrict__ hbuf,
                                                  uint* __restrict__ sync,
                                                  float* __restrict__ out) {
  __shared__ float red[3][4][16][16];   // [gate][wave][b][k]
  const int tid  = threadIdx.x;
  const int lane = tid & 63;
  const int w    = tid >> 6;
  const int quad = lane >> 4, l16 = lane & 15;
  const int kc   = blockIdx.x & 31;     // neuron slice
  const int cb   = blockIdx.x >> 5;     // batch group

  // ---- one-time: XCD discovery, membership, leader election ----
  int xcd = 0; uint nx = 0; bool leader = false;
  if (tid == 0) {
    uint id;
    __asm__ volatile("s_getreg_b32 %0, hwreg(HW_REG_XCC_ID, 0, 32)" : "=s"(id));
    xcd = (int)(id & 7u);
    uint rank = __hip_atomic_fetch_add(&sync[(T_*17 + xcd)*CSTRIDE], 1u,
                                       __ATOMIC_RELAXED, __HIP_MEMORY_SCOPE_AGENT);
    uint* ic = &sync[(T_*17 + 8)*CSTRIDE];
    __hip_atomic_fetch_add(ic, 1u, __ATOMIC_RELEASE, __HIP_MEMORY_SCOPE_AGENT);
    while (aload_rlx(ic) < 256u) __builtin_amdgcn_s_sleep(1);
    (void)__hip_atomic_load(ic, __ATOMIC_ACQUIRE, __HIP_MEMORY_SCOPE_AGENT);
    nx = aload_rlx(&sync[(T_*17 + xcd)*CSTRIDE]);
    leader = (rank == 0u);
  }
  __syncthreads();

  // ---- Wh fragments resident (split-bf16, 3-term) ----
  bf16x8 Bhi[3][4], Blo[3][4];
  #pragma unroll
  for (int g = 0; g < 3; ++g)
    #pragma unroll
    for (int kk = 0; kk < 4; ++kk) {
      const float* p = Wh + (long)(g*HID + kc*16 + l16) * HID + w*128 + kk*32 + quad*8;
      float4 f0 = ((const float4*)p)[0], f1 = ((const float4*)p)[1];
      split8(f0, f1, Bhi[g][kk], Blo[g][kk]);
    }

  const int bb   = tid >> 4;            // 0..15 local batch (gates phase)
  const int kk_  = tid & 15;            // 0..15 local neuron (gates phase)
  const int brow = cb*16 + bb;          // global batch
  const int ncol = kc*16 + kk_;         // global neuron
  float* yout = out;
  float* hfin = out + (long)B_ * T_ * HID;

  uint* const hb0 = hbuf;
  uint* const hb1 = hbuf + 65536;

  for (int t = 0; t < T_; ++t) {
    // --- x_lin prefetch: independent of h, issue BEFORE the wait ---
    float xz, xr, xn;
    {
      const long mrow = (long)brow * T_ + t;
      if (WSF32) {
        const float* xp = (const float*)xlin + mrow * NG + ncol;
        xz = xp[0]; xr = xp[HID]; xn = xp[2*HID];
      } else {
        const unsigned short* xp = (const unsigned short*)xlin + mrow * NG + ncol;
        xz = bf2f(xp[0]); xr = bf2f(xp[HID]); xn = bf2f(xp[2*HID]);
      }
    }

    // --- consume-side wait for step t-1 ---
    if (t > 0) {
      if (tid == 0) {
        uint* fp = &sync[(T_*9 + (t-1)*8 + xcd)*CSTRIDE];
        if (leader) {
          uint* gp = &sync[(t-1)*CSTRIDE];
          while (aload_rlx(gp) < 256u) __builtin_amdgcn_s_sleep(1);
          (void)__hip_atomic_load(gp, __ATOMIC_ACQUIRE, __HIP_MEMORY_SCOPE_AGENT); // ONE inv/XCD
          __hip_atomic_fetch_add(fp, 1u, __ATOMIC_RELAXED, __HIP_MEMORY_SCOPE_AGENT);
        }
        while (aload_rlx(fp) < 1u) __builtin_amdgcn_s_sleep(1);
      }
      __syncthreads();
    }

    const uint* rb = ((t + 1) & 1) ? hb1 : hb0;
    uint*       wb = (t & 1)       ? hb1 : hb0;

    // --- plain vectorized h loads (fresh: L2 inv'd after producer release) ---
    const uint4* hv = (const uint4*)(rb + (cb*16 + l16)*HID + w*128 + quad*8);
    uint4 u[4][2];
    #pragma unroll
    for (int kk = 0; kk < 4; ++kk) {
      u[kk][0] = hv[kk*8 + 0];
      u[kk][1] = hv[kk*8 + 1];
    }
    const uint hpu = rb[brow*HID + ncol];

    // --- GEMM: wave covers K-slice [w*128, w*128+128) ---
    f32x4 acc[3] = { (f32x4){0,0,0,0}, (f32x4){0,0,0,0}, (f32x4){0,0,0,0} };
    #pragma unroll
    for (int kk = 0; kk < 4; ++kk) {
      bf16x8 ah, al;
      #pragma unroll
      for (int i = 0; i < 4; ++i) {
        uint v0 = ((const uint*)&u[kk][0])[i];
        uint v1 = ((const uint*)&u[kk][1])[i];
        ah[i]   = (short)(v0 >> 16); al[i]   = (short)(v0 & 0xFFFFu);
        ah[i+4] = (short)(v1 >> 16); al[i+4] = (short)(v1 & 0xFFFFu);
      }
      #pragma unroll
      for (int g = 0; g < 3; ++g) {
        acc[g] = __builtin_amdgcn_mfma_f32_16x16x32_bf16(ah, Bhi[g][kk], acc[g], 0, 0, 0);
        acc[g] = __builtin_amdgcn_mfma_f32_16x16x32_bf16(ah, Blo[g][kk], acc[g], 0, 0, 0);
        acc[g] = __builtin_amdgcn_mfma_f32_16x16x32_bf16(al, Bhi[g][kk], acc[g], 0, 0, 0);
      }
    }
    #pragma unroll
    for (int g = 0; g < 3; ++g)
      #pragma unroll
      for (int r = 0; r < 4; ++r)
        red[g][w][quad*4 + r][l16] = acc[g][r];

    const float hp = unpackh(hpu);

    __syncthreads();

    float az = 0.f, ar = 0.f, an = 0.f;
    #pragma unroll
    for (int ww = 0; ww < 4; ++ww) {
      az += red[0][ww][bb][kk_];
      ar += red[1][ww][bb][kk_];
      an += red[2][ww][bb][kk_];
    }
    const float z = 1.f / (1.f + __expf(-(az + xz)));
    const float r = 1.f / (1.f + __expf(-(ar + xr)));
    const float pre = xn + r * an;
    const float e2 = __expf(-2.f * pre);
    const float n = 2.f / (1.f + e2) - 1.f;          // tanh, inf-safe
    const float hn = (1.f - z) * n + z * hp;

    if (t < T_ - 1) {
      wb[brow*HID + ncol] = packh(hn);               // plain store -> own L2
    } else {
      hfin[brow*HID + ncol] = hn;
    }

    // drain h stores into L2, then signal
    __syncthreads();
    if (tid == 0 && t < T_ - 1) {
      uint* lp = &sync[(T_ + t*8 + xcd)*CSTRIDE];
      __hip_atomic_fetch_add(lp, 1u, __ATOMIC_RELAXED, __HIP_MEMORY_SCOPE_AGENT);
      if (leader) {
        while (aload_rlx(lp) < nx) __builtin_amdgcn_s_sleep(1);
        // ONE wbl2/XCD: flushes ALL co-resident WGs' h stores (shared L2)
        __hip_atomic_fetch_add(&sync[t*CSTRIDE], nx, __ATOMIC_RELEASE,
                               __HIP_MEMORY_SCOPE_AGENT);
      }
    }

    // y store AFTER signaling: its HBM ack is off the critical path
    __builtin_nontemporal_store(hn, &yout[((long)brow * T_ + t) * HID + ncol]);
  }
}

// ---------------------------------------------------------------------------
extern "C" void kernel_launch(void* const* d_in, const int* in_sizes, int n_in,
                              void* d_out, int out_size, void* d_ws, size_t ws_size,
                              hipStream_t stream) {
  const float* x  = (const float*)d_in[0];
  const float* h0 = (const float*)d_in[1];
  const float* Wx = (const float*)d_in[2];
  const float* bx = (const float*)d_in[3];
  const float* Wh = (const float*)d_in[4];
  float* out = (float*)d_out;

  const size_t xlin_f32  = (size_t)B_ * T_ * NG * 4;   // 402,653,184
  const size_t xlin_bf16 = (size_t)B_ * T_ * NG * 2;   // 201,326,592
  const size_t hbuf_sz   = (size_t)2 * 65536 * 4;      // 512 KiB (packed uint)
  const size_t sync_u32  = (size_t)(T_*17 + 16) * CSTRIDE;  // gcnt+lcnt+flag+mem+init
  const size_t sync_sz   = sync_u32 * 4;               // ~558 KiB

  const bool wsf32 = (ws_size >= xlin_f32 + hbuf_sz + sync_sz);
  const size_t xsz = wsf32 ? xlin_f32 : xlin_bf16;
  void* xlin = d_ws;
  uint* hbuf = (uint*)((char*)d_ws + xsz);
  uint* sync = (uint*)((char*)d_ws + xsz + hbuf_sz);

  hipMemsetAsync(sync, 0, sync_sz, stream);
  h0_pack<<<256, 256, 0, stream>>>(h0, hbuf);
  if (wsf32) {
    xlin_kernel<true ><<<dim3(12, 512), 256, 0, stream>>>(x, Wx, bx, xlin);
    gru_rec<true >    <<<256, 256, 0, stream>>>(xlin, Wh, hbuf, sync, out);
  } else {
    xlin_kernel<false><<<dim3(12, 512), 256, 0, stream>>>(x, Wx, bx, xlin);
    gru_rec<false>    <<<256, 256, 0, stream>>>(xlin, Wh, hbuf, sync, out);
  }
}